// Round 3
// baseline (564.970 us; speedup 1.0000x reference)
//
#include <hip/hip_runtime.h>
#include <hip/hip_bf16.h>
#include <cstdint>
#include <cstddef>

#define VV 50000
#define HH 1024
#define NROWS 4096
#define VPAD 50048      // 391*128
#define NCOLT 391
#define NCHUNK 782      // 50048/64
#define SP1 4000
#define SP2 20000
#define SP3 50000
#define VTOT 50002      // 50000 + 2 tail-cluster columns

#define BM 256
#define BN 128
#define BK 64
#define NKT (HH / BK)           // 16
#define A_SLOT_E (BM * BK)      // 16384 elems
#define B_SLOT_E (BN * BK)      // 8192 elems
#define SLOT_E (A_SLOT_E + B_SLOT_E)  // 24576 elems = 48 KiB

typedef __attribute__((ext_vector_type(8))) short short8;
typedef __attribute__((ext_vector_type(4))) float f32x4;
typedef __attribute__((ext_vector_type(4))) unsigned short us4;

typedef __attribute__((address_space(1))) unsigned int uint_g;
typedef __attribute__((address_space(3))) unsigned int uint_l;

__device__ __forceinline__ void gload16(const void* g, void* l) {
  __builtin_amdgcn_global_load_lds((const uint_g*)g, (uint_l*)l, 16, 0, 0);
}

__device__ __forceinline__ unsigned short f2bf(float f) {
  __hip_bfloat16 h = __float2bfloat16(f);
  return *reinterpret_cast<unsigned short*>(&h);
}

// ---- convert weight + tail_vectors -> bf16, padded to VPAD rows ----
__global__ void convW(const float* __restrict__ w, const float* __restrict__ tails,
                      unsigned short* __restrict__ Wb) {
  const size_t nq = (size_t)VPAD * HH / 4;
  for (size_t q = (size_t)blockIdx.x * blockDim.x + threadIdx.x; q < nq;
       q += (size_t)gridDim.x * blockDim.x) {
    const size_t e = q * 4;
    const int row = (int)(e >> 10);
    us4 o;
    if (row < VV) {
      float4 f = *(const float4*)(w + e);
      o = (us4){f2bf(f.x), f2bf(f.y), f2bf(f.z), f2bf(f.w)};
    } else if (row < VTOT) {
      float4 f = *(const float4*)(tails + (e - (size_t)VV * HH));
      o = (us4){f2bf(f.x), f2bf(f.y), f2bf(f.z), f2bf(f.w)};
    } else {
      o = (us4){0, 0, 0, 0};
    }
    *(us4*)(Wb + e) = o;
  }
}

__global__ void convH(const float* __restrict__ h, unsigned short* __restrict__ Hb) {
  const size_t nq = (size_t)NROWS * HH / 4;
  for (size_t q = (size_t)blockIdx.x * blockDim.x + threadIdx.x; q < nq;
       q += (size_t)gridDim.x * blockDim.x) {
    const size_t e = q * 4;
    float4 f = *(const float4*)(h + e);
    us4 o = (us4){f2bf(f.x), f2bf(f.y), f2bf(f.z), f2bf(f.w)};
    *(us4*)(Hb + e) = o;
  }
}

// ---- main GEMM + segment-partial-sumexp epilogue ----
// grid (16 rowTiles, 391 colTiles), 512 threads (8 waves = 4M x 2N, per-wave 64x64)
// 3-slot LDS ring, distance-2 prefetch, counted vmcnt, XOR-swizzled tiles,
// 2 phases per K-tile (kk-split): {ds_read || stage -> barrier -> prio(1) 16 MFMA prio(0) -> [vmcnt] -> barrier}
__global__ __launch_bounds__(512) void gemm_lse(
    const unsigned short* __restrict__ Wb, const unsigned short* __restrict__ Hb,
    const float* __restrict__ bias, const float* __restrict__ tail_bias,
    float* __restrict__ partials /* [3][NROWS][NCHUNK] */) {
  __shared__ __align__(16) unsigned short lds[3 * SLOT_E];  // 147456 B

  const int tid = threadIdx.x;
  const int w = tid >> 6, lane = tid & 63;
  const int wr = w >> 1, wc = w & 1;
  const int fr = lane & 15, fq = lane >> 4;
  const int rowTile = blockIdx.x, colTile = blockIdx.y;
  const unsigned short* Ag = Hb + (size_t)rowTile * BM * HH;
  const unsigned short* Bg = Wb + (size_t)colTile * BN * HH;

  // staging offsets: linear LDS dest, inverse-swizzled global source
  int srcA[4], srcB[2];
  const int dcb = (tid & 7) << 4;  // dest byte-col within 128B row
#pragma unroll
  for (int i = 0; i < 4; i++) {
    const int R = (i * 512 + tid) >> 3;
    srcA[i] = R * HH + ((dcb ^ ((R & 7) << 4)) >> 1);
  }
#pragma unroll
  for (int i = 0; i < 2; i++) {
    const int R = (i * 512 + tid) >> 3;
    srcB[i] = R * HH + ((dcb ^ ((R & 7) << 4)) >> 1);
  }

  // fragment read offsets (swizzled), elements within slot
  int offA[4][2], offB[4][2];
#pragma unroll
  for (int mi = 0; mi < 4; mi++) {
    const int R = wr * 64 + mi * 16 + fr;
#pragma unroll
    for (int kk = 0; kk < 2; kk++) {
      const int cb = kk * 64 + fq * 16;
      offA[mi][kk] = R * 64 + ((cb ^ ((R & 7) << 4)) >> 1);
    }
  }
#pragma unroll
  for (int ni = 0; ni < 4; ni++) {
    const int R = wc * 64 + ni * 16 + fr;
#pragma unroll
    for (int kk = 0; kk < 2; kk++) {
      const int cb = kk * 64 + fq * 16;
      offB[ni][kk] = R * 64 + ((cb ^ ((R & 7) << 4)) >> 1);
    }
  }

  f32x4 acc[4][4];
#pragma unroll
  for (int i = 0; i < 4; i++)
#pragma unroll
    for (int j = 0; j < 4; j++) acc[i][j] = (f32x4){0.f, 0.f, 0.f, 0.f};

  // chunk 0: A rows 0-127; chunk 1: A rows 128-255; chunk 2: B (all 128 rows)
  auto STAGE_CHUNK = [&](int t, int chunk) {
    const int slot = t % 3;
    unsigned short* Asl = (unsigned short*)lds + slot * SLOT_E;
    unsigned short* Bsl = Asl + A_SLOT_E;
    const int k0 = t * BK;
    if (chunk == 0) {
#pragma unroll
      for (int i = 0; i < 2; i++)
        gload16(Ag + (size_t)srcA[i] + k0, Asl + (i * 512 + tid) * 8);
    } else if (chunk == 1) {
#pragma unroll
      for (int i = 2; i < 4; i++)
        gload16(Ag + (size_t)srcA[i] + k0, Asl + (i * 512 + tid) * 8);
    } else {
#pragma unroll
      for (int i = 0; i < 2; i++)
        gload16(Bg + (size_t)srcB[i] + k0, Bsl + (i * 512 + tid) * 8);
    }
  };

  // prologue: tiles 0 and 1 fully staged; wait for tile 0 (6 of 12 outstanding)
  STAGE_CHUNK(0, 0);
  STAGE_CHUNK(0, 1);
  STAGE_CHUNK(0, 2);
  STAGE_CHUNK(1, 0);
  STAGE_CHUNK(1, 1);
  STAGE_CHUNK(1, 2);
  asm volatile("s_waitcnt vmcnt(6)" ::: "memory");
  __builtin_amdgcn_s_barrier();

  for (int t = 0; t < NKT; ++t) {
    const unsigned short* Asl = (const unsigned short*)lds + (t % 3) * SLOT_E;
    const unsigned short* Bsl = Asl + A_SLOT_E;
    const bool pf = (t + 2 < NKT);
#pragma unroll
    for (int kk = 0; kk < 2; kk++) {
      short8 a[4], b[4];
#pragma unroll
      for (int mi = 0; mi < 4; mi++) a[mi] = *(const short8*)&Asl[offA[mi][kk]];
#pragma unroll
      for (int ni = 0; ni < 4; ni++) b[ni] = *(const short8*)&Bsl[offB[ni][kk]];
      if (kk == 0) {
        if (pf) {
          STAGE_CHUNK(t + 2, 0);
          STAGE_CHUNK(t + 2, 1);
        }
      } else {
        if (pf) STAGE_CHUNK(t + 2, 2);
      }
      __builtin_amdgcn_s_barrier();
      __builtin_amdgcn_s_setprio(1);
#pragma unroll
      for (int mi = 0; mi < 4; mi++)
#pragma unroll
        for (int ni = 0; ni < 4; ni++)
          acc[mi][ni] =
              __builtin_amdgcn_mfma_f32_16x16x32_bf16(a[mi], b[ni], acc[mi][ni], 0, 0, 0);
      __builtin_amdgcn_s_setprio(0);
      if (kk == 1) {
        if (pf)
          asm volatile("s_waitcnt vmcnt(6)" ::: "memory");
        else if (t + 1 < NKT)
          asm volatile("s_waitcnt vmcnt(0)" ::: "memory");
      }
      __builtin_amdgcn_s_barrier();
    }
  }

  // ---- epilogue: per-(row, 64-col chunk, segment) sum of exp(logit + bias) ----
  const int colw = colTile * BN + wc * 64;  // wave's col base
  float biasv[4], validf[4];
  int segv[4];
#pragma unroll
  for (int ni = 0; ni < 4; ni++) {
    const int col = colw + ni * 16 + fr;
    const bool valid = col < VTOT;
    float b = 0.f;
    if (col < VV) b = bias[col];
    else if (valid) b = tail_bias[col - VV];
    biasv[ni] = b;
    segv[ni] = (col < SP1) ? 0 : (col < SP2) ? 1 : (col < SP3) ? 2 : 0;
    validf[ni] = valid ? 1.f : 0.f;
  }
  const int segLo = (colw < SP1) ? 0 : (colw < SP2) ? 1 : (colw < SP3) ? 2 : 0;
  const int colHi = colw + 63;
  const int segHi = (colHi < SP1) ? 0 : (colHi < SP2) ? 1 : (colHi < SP3) ? 2 : 0;
  const bool oneseg = (segLo == segHi) && (colHi < VTOT);

  const int chunk = colTile * 2 + wc;
  const size_t segStride = (size_t)NROWS * NCHUNK;

#pragma unroll
  for (int mi = 0; mi < 4; mi++) {
    const int rowg = rowTile * BM + wr * 64 + mi * 16 + fq * 4;
    if (oneseg) {
#pragma unroll
      for (int r = 0; r < 4; r++) {
        float p = 0.f;
#pragma unroll
        for (int ni = 0; ni < 4; ni++)
          p += validf[ni] * __expf(acc[mi][ni][r] + biasv[ni]);
#pragma unroll
        for (int m = 1; m < 16; m <<= 1) p += __shfl_xor(p, m);
        if (fr == 0) {
          const size_t base = (size_t)(rowg + r) * NCHUNK + chunk;
          partials[(size_t)segLo * segStride + base] = p;
          partials[(size_t)((segLo + 1) % 3) * segStride + base] = 0.f;
          partials[(size_t)((segLo + 2) % 3) * segStride + base] = 0.f;
        }
      }
    } else {
#pragma unroll
      for (int r = 0; r < 4; r++) {
        float p0 = 0.f, p1 = 0.f, p2 = 0.f;
#pragma unroll
        for (int ni = 0; ni < 4; ni++) {
          const float e = validf[ni] * __expf(acc[mi][ni][r] + biasv[ni]);
          p0 += (segv[ni] == 0) ? e : 0.f;
          p1 += (segv[ni] == 1) ? e : 0.f;
          p2 += (segv[ni] == 2) ? e : 0.f;
        }
#pragma unroll
        for (int m = 1; m < 16; m <<= 1) {
          p0 += __shfl_xor(p0, m);
          p1 += __shfl_xor(p1, m);
          p2 += __shfl_xor(p2, m);
        }
        if (fr == 0) {
          const size_t base = (size_t)(rowg + r) * NCHUNK + chunk;
          partials[0 * segStride + base] = p0;
          partials[1 * segStride + base] = p1;
          partials[2 * segStride + base] = p2;
        }
      }
    }
  }
}

// ---- per-row: combine chunk partials, compute selected logits in fp32, loss ----
__global__ __launch_bounds__(256) void rowloss(
    const float* __restrict__ partials, const float* __restrict__ hiddens,
    const float* __restrict__ weight, const float* __restrict__ bias,
    const float* __restrict__ tails, const float* __restrict__ tail_bias,
    const int* __restrict__ targets, float* __restrict__ losses) {
  const int row = blockIdx.x * 4 + (threadIdx.x >> 6);
  const int lane = threadIdx.x & 63;
  const size_t segStride = (size_t)NROWS * NCHUNK;
  const float* P0 = partials + (size_t)row * NCHUNK;
  const float* P1 = P0 + segStride;
  const float* P2 = P1 + segStride;
  float s0 = 0.f, s1 = 0.f, s2 = 0.f;
  for (int c = lane; c < NCHUNK; c += 64) {
    s0 += P0[c];
    s1 += P1[c];
    s2 += P2[c];
  }
#pragma unroll
  for (int m = 1; m < 64; m <<= 1) {
    s0 += __shfl_xor(s0, m);
    s1 += __shfl_xor(s1, m);
    s2 += __shfl_xor(s2, m);
  }
  const int t = targets[row];
  const int cl = (t >= SP1) + (t >= SP2);
  const float* hv = hiddens + (size_t)row * HH;
  const float* w1;
  float b1;
  if (cl == 0) {
    w1 = weight + (size_t)t * HH;
    b1 = bias[t];
  } else if (cl == 1) {
    w1 = tails + HH;  // head col 4001 <-> tail_vectors[1]
    b1 = tail_bias[1];
  } else {
    w1 = tails;       // head col 4000 <-> tail_vectors[0]
    b1 = tail_bias[0];
  }
  float d1 = 0.f, d2 = 0.f;
  for (int i = lane; i < HH; i += 64) d1 += hv[i] * w1[i];
  if (cl > 0) {
    const float* w2 = weight + (size_t)t * HH;
    for (int i = lane; i < HH; i += 64) d2 += hv[i] * w2[i];
  }
#pragma unroll
  for (int m = 1; m < 64; m <<= 1) {
    d1 += __shfl_xor(d1, m);
    d2 += __shfl_xor(d2, m);
  }
  if (lane == 0) {
    float loss = logf(s0) - (d1 + b1);
    if (cl == 1) loss += logf(s1) - (d2 + bias[t]);
    if (cl == 2) loss += logf(s2) - (d2 + bias[t]);
    losses[row] = loss;
  }
}

__global__ void meanloss(const float* __restrict__ losses, float* __restrict__ out) {
  __shared__ float red[256];
  float s = 0.f;
  for (int i = threadIdx.x; i < NROWS; i += 256) s += losses[i];
  red[threadIdx.x] = s;
  __syncthreads();
  for (int st = 128; st > 0; st >>= 1) {
    if ((int)threadIdx.x < st) red[threadIdx.x] += red[threadIdx.x + st];
    __syncthreads();
  }
  if (threadIdx.x == 0) out[0] = red[0] / (float)NROWS;
}

extern "C" void kernel_launch(void* const* d_in, const int* in_sizes, int n_in,
                              void* d_out, int out_size, void* d_ws, size_t ws_size,
                              hipStream_t stream) {
  const float* weight = (const float*)d_in[0];
  const float* bias = (const float*)d_in[1];
  const float* hiddens = (const float*)d_in[2];
  const float* tails = (const float*)d_in[3];
  const float* tail_bias = (const float*)d_in[4];
  const int* targets = (const int*)d_in[5];
  float* out = (float*)d_out;

  char* ws = (char*)d_ws;
  unsigned short* Wb = (unsigned short*)ws;                    // 50048*1024*2 = 102,498,304 B
  unsigned short* Hb = (unsigned short*)(ws + 102498304);      // 4096*1024*2  =   8,388,608 B
  float* partials = (float*)(ws + 110886912);                  // 3*4096*782*4 =  38,436,864 B
  float* losses = (float*)(ws + 149323776);                    // 4096*4       =      16,384 B

  hipLaunchKernelGGL(convW, dim3(2048), dim3(256), 0, stream, weight, tails, Wb);
  hipLaunchKernelGGL(convH, dim3(512), dim3(256), 0, stream, hiddens, Hb);
  hipLaunchKernelGGL(gemm_lse, dim3(NROWS / BM, NCOLT), dim3(512), 0, stream, Wb, Hb,
                     bias, tail_bias, partials);
  hipLaunchKernelGGL(rowloss, dim3(NROWS / 4), dim3(256), 0, stream, partials, hiddens,
                     weight, bias, tails, tail_bias, targets, losses);
  hipLaunchKernelGGL(meanloss, dim3(1), dim3(256), 0, stream, losses, out);
}

// Round 4
// 540.873 us; speedup vs baseline: 1.0446x; 1.0446x over previous
//
#include <hip/hip_runtime.h>
#include <hip/hip_bf16.h>
#include <cstdint>
#include <cstddef>

#define VV 50000
#define HH 1024
#define NROWS 4096
#define VPAD 50176      // 196*256, padded reordered-W rows
#define SP1 4000
#define SP2 20000
#define SP3 50000

#define BM 256
#define BN 128
#define BK 64
#define NKT (HH / BK)           // 16
#define A_SLOT_E (BM * BK)      // 16384 elems
#define B_SLOT_E (BN * BK)      // 8192 elems
#define SLOT_E (A_SLOT_E + B_SLOT_E)  // 24576 elems = 48 KiB

// reordered-W column map: [0..3999]=weight, [4000..4001]=tail_vectors,
// [4002..50001]=weight[4000..49999], rest zero-pad
#define CB_T1 4002
#define CB_T2 20002
#define CL_HEAD 4002
#define CL_T1 20002
#define CL_T2 50002
#define CT_HEAD 32
#define CT_T1 125
#define CT_T2 235
#define PH_STRIDE 64    // 2*CT_HEAD
#define PT1_STRIDE 250  // 2*CT_T1
#define PT2_STRIDE 470  // 2*CT_T2

typedef __attribute__((ext_vector_type(8))) short short8;
typedef __attribute__((ext_vector_type(4))) float f32x4;
typedef __attribute__((ext_vector_type(4))) unsigned short us4;

typedef __attribute__((address_space(1))) unsigned int uint_g;
typedef __attribute__((address_space(3))) unsigned int uint_l;

__device__ __forceinline__ void gload16(const void* g, void* l) {
  __builtin_amdgcn_global_load_lds((const uint_g*)g, (uint_l*)l, 16, 0, 0);
}

__device__ __forceinline__ unsigned short f2bf(float f) {
  __hip_bfloat16 h = __float2bfloat16(f);
  return *reinterpret_cast<unsigned short*>(&h);
}

// ---- convert weight + tail_vectors -> bf16, reordered, padded to VPAD rows ----
__global__ void convW(const float* __restrict__ w, const float* __restrict__ tails,
                      unsigned short* __restrict__ Wb) {
  const size_t nq = (size_t)VPAD * HH / 4;
  for (size_t q = (size_t)blockIdx.x * blockDim.x + threadIdx.x; q < nq;
       q += (size_t)gridDim.x * blockDim.x) {
    const size_t e = q * 4;
    const int row = (int)(e >> 10);
    us4 o;
    if (row < 4000) {
      float4 f = *(const float4*)(w + e);
      o = (us4){f2bf(f.x), f2bf(f.y), f2bf(f.z), f2bf(f.w)};
    } else if (row < 4002) {
      float4 f = *(const float4*)(tails + (e - (size_t)4000 * HH));
      o = (us4){f2bf(f.x), f2bf(f.y), f2bf(f.z), f2bf(f.w)};
    } else if (row < 50002) {
      float4 f = *(const float4*)(w + (e - 2048));
      o = (us4){f2bf(f.x), f2bf(f.y), f2bf(f.z), f2bf(f.w)};
    } else {
      o = (us4){0, 0, 0, 0};
    }
    *(us4*)(Wb + e) = o;
  }
}

// reordered bias (pads get -1e30 so exp() underflows to 0)
__global__ void biasK(const float* __restrict__ bias, const float* __restrict__ tb,
                      float* __restrict__ biasr) {
  const int r = blockIdx.x * 256 + threadIdx.x;
  if (r >= VPAD) return;
  float v;
  if (r < 4000) v = bias[r];
  else if (r == 4000) v = tb[0];
  else if (r == 4001) v = tb[1];
  else if (r < 50002) v = bias[r - 2];
  else v = -1e30f;
  biasr[r] = v;
}

__global__ void convH(const float* __restrict__ h, unsigned short* __restrict__ Hb) {
  const size_t nq = (size_t)NROWS * HH / 4;
  for (size_t q = (size_t)blockIdx.x * blockDim.x + threadIdx.x; q < nq;
       q += (size_t)gridDim.x * blockDim.x) {
    const size_t e = q * 4;
    float4 f = *(const float4*)(h + e);
    us4 o = (us4){f2bf(f.x), f2bf(f.y), f2bf(f.z), f2bf(f.w)};
    *(us4*)(Hb + e) = o;
  }
}

// ---- deterministic cluster scan: compact index per row, counts ----
__global__ __launch_bounds__(1024) void scanK(const int* __restrict__ targets,
                                              int* __restrict__ cidx,
                                              int* __restrict__ counts) {
  __shared__ int s1[1024], s2[1024];
  const int tid = threadIdx.x;
  int c[4];
  int n1 = 0, n2 = 0;
#pragma unroll
  for (int j = 0; j < 4; j++) {
    const int t = targets[tid * 4 + j];
    c[j] = (t >= SP1) + (t >= SP2);
    n1 += (c[j] == 1);
    n2 += (c[j] == 2);
  }
  s1[tid] = n1;
  s2[tid] = n2;
  __syncthreads();
  for (int off = 1; off < 1024; off <<= 1) {
    const int a1 = (tid >= off) ? s1[tid - off] : 0;
    const int a2 = (tid >= off) ? s2[tid - off] : 0;
    __syncthreads();
    s1[tid] += a1;
    s2[tid] += a2;
    __syncthreads();
  }
  int e1 = s1[tid] - n1, e2 = s2[tid] - n2;
#pragma unroll
  for (int j = 0; j < 4; j++) {
    if (c[j] == 1) cidx[tid * 4 + j] = e1++;
    else if (c[j] == 2) cidx[tid * 4 + j] = e2++;
    else cidx[tid * 4 + j] = 0;
  }
  if (tid == 1023) {
    counts[0] = s1[1023];
    counts[1] = s2[1023];
    counts[2] = NROWS;
  }
}

// zero both compact-H buffers (contiguous)
__global__ void zeroHc(unsigned short* __restrict__ Hc) {
  const size_t n8 = (size_t)2 * NROWS * HH / 8;
  const short8 z = (short8){0, 0, 0, 0, 0, 0, 0, 0};
  for (size_t i = (size_t)blockIdx.x * blockDim.x + threadIdx.x; i < n8;
       i += (size_t)gridDim.x * blockDim.x)
    *((short8*)Hc + i) = z;
}

// gather bf16 H rows into per-cluster compact matrices (1 wave per row)
__global__ __launch_bounds__(256) void gatherK(const unsigned short* __restrict__ Hb,
                                               const int* __restrict__ targets,
                                               const int* __restrict__ cidx,
                                               unsigned short* __restrict__ Hc1,
                                               unsigned short* __restrict__ Hc2) {
  const int row = blockIdx.x * 4 + (threadIdx.x >> 6);
  const int lane = threadIdx.x & 63;
  const int t = targets[row];
  const int cl = (t >= SP1) + (t >= SP2);
  if (cl == 0) return;
  unsigned short* dst = (cl == 1 ? Hc1 : Hc2) + (size_t)cidx[row] * HH;
  const unsigned short* src = Hb + (size_t)row * HH;
#pragma unroll
  for (int j = 0; j < 2; j++) {
    const int i = j * 512 + lane * 8;
    *(short8*)(dst + i) = *(const short8*)(src + i);
  }
}

// ---- GEMM + single-segment sum-exp epilogue (round-2 proven structure) ----
// grid (16 rowTiles, colTiles), 512 threads (8 waves = 4M x 2N, wave 64x64)
// 3-slot LDS ring, distance-2 prefetch, counted vmcnt(6), XOR-swizzle.
__global__ __launch_bounds__(512) void gemm_lse(
    const unsigned short* __restrict__ Ab, const unsigned short* __restrict__ Wb,
    int colbase, int col_limit, const float* __restrict__ biasr,
    float* __restrict__ partials, const int* __restrict__ Mptr, int mslot) {
  const int Mc = Mptr[mslot];
  const int rowTile = blockIdx.x;
  if (rowTile * BM >= Mc) return;
  const int colTile = blockIdx.y;

  __shared__ __align__(16) unsigned short lds[3 * SLOT_E];  // 147456 B

  const int tid = threadIdx.x;
  const int w = tid >> 6, lane = tid & 63;
  const int wr = w >> 1, wc = w & 1;
  const int fr = lane & 15, fq = lane >> 4;
  const unsigned short* Ag = Ab + (size_t)rowTile * BM * HH;
  const unsigned short* Bg = Wb + (size_t)(colbase + colTile * BN) * HH;

  // staging offsets: linear LDS dest, inverse-swizzled global source
  int srcA[4], srcB[2];
  const int dcb = (tid & 7) << 4;  // dest byte-col within 128B row
#pragma unroll
  for (int i = 0; i < 4; i++) {
    const int R = (i * 512 + tid) >> 3;
    srcA[i] = R * HH + ((dcb ^ ((R & 7) << 4)) >> 1);
  }
#pragma unroll
  for (int i = 0; i < 2; i++) {
    const int R = (i * 512 + tid) >> 3;
    srcB[i] = R * HH + ((dcb ^ ((R & 7) << 4)) >> 1);
  }

  // fragment read offsets (swizzled), elements within slot
  int offA[4][2], offB[4][2];
#pragma unroll
  for (int mi = 0; mi < 4; mi++) {
    const int R = wr * 64 + mi * 16 + fr;
#pragma unroll
    for (int kk = 0; kk < 2; kk++) {
      const int cb = kk * 64 + fq * 16;
      offA[mi][kk] = R * 64 + ((cb ^ ((R & 7) << 4)) >> 1);
    }
  }
#pragma unroll
  for (int ni = 0; ni < 4; ni++) {
    const int R = wc * 64 + ni * 16 + fr;
#pragma unroll
    for (int kk = 0; kk < 2; kk++) {
      const int cb = kk * 64 + fq * 16;
      offB[ni][kk] = R * 64 + ((cb ^ ((R & 7) << 4)) >> 1);
    }
  }

  f32x4 acc[4][4];
#pragma unroll
  for (int i = 0; i < 4; i++)
#pragma unroll
    for (int j = 0; j < 4; j++) acc[i][j] = (f32x4){0.f, 0.f, 0.f, 0.f};

  auto STAGE = [&](int t) {
    const int slot = t % 3;
    unsigned short* Asl = (unsigned short*)lds + slot * SLOT_E;
    unsigned short* Bsl = Asl + A_SLOT_E;
    const int k0 = t * BK;
#pragma unroll
    for (int i = 0; i < 4; i++)
      gload16(Ag + (size_t)srcA[i] + k0, Asl + (i * 512 + tid) * 8);
#pragma unroll
    for (int i = 0; i < 2; i++)
      gload16(Bg + (size_t)srcB[i] + k0, Bsl + (i * 512 + tid) * 8);
  };

  STAGE(0);
  STAGE(1);

  for (int t = 0; t < NKT; ++t) {
    if (t < NKT - 1)
      asm volatile("s_waitcnt vmcnt(6)" ::: "memory");
    else
      asm volatile("s_waitcnt vmcnt(0)" ::: "memory");
    __builtin_amdgcn_s_barrier();
    if (t + 2 < NKT) STAGE(t + 2);

    const unsigned short* Asl = (const unsigned short*)lds + (t % 3) * SLOT_E;
    const unsigned short* Bsl = Asl + A_SLOT_E;
#pragma unroll
    for (int kk = 0; kk < 2; kk++) {
      short8 a[4], b[4];
#pragma unroll
      for (int mi = 0; mi < 4; mi++) a[mi] = *(const short8*)&Asl[offA[mi][kk]];
#pragma unroll
      for (int ni = 0; ni < 4; ni++) b[ni] = *(const short8*)&Bsl[offB[ni][kk]];
      __builtin_amdgcn_s_setprio(1);
#pragma unroll
      for (int mi = 0; mi < 4; mi++)
#pragma unroll
        for (int ni = 0; ni < 4; ni++)
          acc[mi][ni] =
              __builtin_amdgcn_mfma_f32_16x16x32_bf16(a[mi], b[ni], acc[mi][ni], 0, 0, 0);
      __builtin_amdgcn_s_setprio(0);
    }
    __builtin_amdgcn_s_barrier();
  }

  // ---- epilogue: per-(row, 64-col chunk) sum of exp(logit + bias) ----
  const int colw = colTile * BN + wc * 64;
  float biasv[4];
#pragma unroll
  for (int ni = 0; ni < 4; ni++) {
    const int gcol = colbase + colw + ni * 16 + fr;
    biasv[ni] = (gcol < col_limit) ? biasr[gcol] : -1e30f;
  }
  const int chunk = colTile * 2 + wc;
  const int pstride = (int)gridDim.y * 2;

#pragma unroll
  for (int mi = 0; mi < 4; mi++) {
    const int rowg = rowTile * BM + wr * 64 + mi * 16 + fq * 4;
#pragma unroll
    for (int r = 0; r < 4; r++) {
      float p = 0.f;
#pragma unroll
      for (int ni = 0; ni < 4; ni++) p += __expf(acc[mi][ni][r] + biasv[ni]);
#pragma unroll
      for (int m = 1; m < 16; m <<= 1) p += __shfl_xor(p, m);
      if (fr == 0) partials[(size_t)(rowg + r) * pstride + chunk] = p;
    }
  }
}

// ---- per-row: combine chunk partials, selected logits in fp32, loss ----
__global__ __launch_bounds__(256) void rowloss(
    const float* __restrict__ ph, const float* __restrict__ pt1,
    const float* __restrict__ pt2, const int* __restrict__ cidx,
    const float* __restrict__ hiddens, const float* __restrict__ weight,
    const float* __restrict__ bias, const float* __restrict__ tails,
    const float* __restrict__ tail_bias, const int* __restrict__ targets,
    float* __restrict__ losses) {
  const int row = blockIdx.x * 4 + (threadIdx.x >> 6);
  const int lane = threadIdx.x & 63;
  const int t = targets[row];
  const int cl = (t >= SP1) + (t >= SP2);

  float s0 = ph[(size_t)row * PH_STRIDE + lane];  // exactly 64 chunks
  float st = 0.f;
  if (cl == 1) {
    const float* P = pt1 + (size_t)cidx[row] * PT1_STRIDE;
    for (int c = lane; c < PT1_STRIDE; c += 64) st += P[c];
  } else if (cl == 2) {
    const float* P = pt2 + (size_t)cidx[row] * PT2_STRIDE;
    for (int c = lane; c < PT2_STRIDE; c += 64) st += P[c];
  }
#pragma unroll
  for (int m = 1; m < 64; m <<= 1) {
    s0 += __shfl_xor(s0, m);
    st += __shfl_xor(st, m);
  }

  const float* hv = hiddens + (size_t)row * HH;
  const float* w1;
  float b1;
  if (cl == 0) {
    w1 = weight + (size_t)t * HH;
    b1 = bias[t];
  } else if (cl == 1) {
    w1 = tails + HH;  // head col 4001 <-> tail_vectors[1]
    b1 = tail_bias[1];
  } else {
    w1 = tails;       // head col 4000 <-> tail_vectors[0]
    b1 = tail_bias[0];
  }
  float d1 = 0.f, d2 = 0.f;
  for (int i = lane; i < HH; i += 64) d1 += hv[i] * w1[i];
  if (cl > 0) {
    const float* w2 = weight + (size_t)t * HH;
    for (int i = lane; i < HH; i += 64) d2 += hv[i] * w2[i];
  }
#pragma unroll
  for (int m = 1; m < 64; m <<= 1) {
    d1 += __shfl_xor(d1, m);
    d2 += __shfl_xor(d2, m);
  }
  if (lane == 0) {
    float loss = logf(s0) - (d1 + b1);
    if (cl > 0) loss += logf(st) - (d2 + bias[t]);
    losses[row] = loss;
  }
}

__global__ void meanloss(const float* __restrict__ losses, float* __restrict__ out) {
  __shared__ float red[256];
  float s = 0.f;
  for (int i = threadIdx.x; i < NROWS; i += 256) s += losses[i];
  red[threadIdx.x] = s;
  __syncthreads();
  for (int st = 128; st > 0; st >>= 1) {
    if ((int)threadIdx.x < st) red[threadIdx.x] += red[threadIdx.x + st];
    __syncthreads();
  }
  if (threadIdx.x == 0) out[0] = red[0] / (float)NROWS;
}

extern "C" void kernel_launch(void* const* d_in, const int* in_sizes, int n_in,
                              void* d_out, int out_size, void* d_ws, size_t ws_size,
                              hipStream_t stream) {
  const float* weight = (const float*)d_in[0];
  const float* bias = (const float*)d_in[1];
  const float* hiddens = (const float*)d_in[2];
  const float* tails = (const float*)d_in[3];
  const float* tail_bias = (const float*)d_in[4];
  const int* targets = (const int*)d_in[5];
  float* out = (float*)d_out;

  char* ws = (char*)d_ws;
  unsigned short* Wb = (unsigned short*)ws;                     // 50176*1024*2 = 102,760,448
  unsigned short* Hb = (unsigned short*)(ws + 102760448);       //  8,388,608
  unsigned short* Hc1 = (unsigned short*)(ws + 111149056);      //  8,388,608
  unsigned short* Hc2 = (unsigned short*)(ws + 119537664);      //  8,388,608 (contig w/ Hc1)
  float* ph = (float*)(ws + 127926272);                         //  4096*64*4  = 1,048,576
  float* pt1 = (float*)(ws + 128974848);                        //  4096*250*4 = 4,096,000
  float* pt2 = (float*)(ws + 133070848);                        //  4096*470*4 = 7,700,480
  float* biasr = (float*)(ws + 140771328);                      //  50176*4    = 200,704
  int* cidx = (int*)(ws + 140972032);                           //  16,384
  int* counts = (int*)(ws + 140988416);                         //  64
  float* losses = (float*)(ws + 140988480);                     //  16,384

  hipLaunchKernelGGL(convW, dim3(2048), dim3(256), 0, stream, weight, tails, Wb);
  hipLaunchKernelGGL(biasK, dim3((VPAD + 255) / 256), dim3(256), 0, stream, bias,
                     tail_bias, biasr);
  hipLaunchKernelGGL(convH, dim3(512), dim3(256), 0, stream, hiddens, Hb);
  hipLaunchKernelGGL(scanK, dim3(1), dim3(1024), 0, stream, targets, cidx, counts);
  hipLaunchKernelGGL(zeroHc, dim3(1024), dim3(256), 0, stream, Hc1);
  hipLaunchKernelGGL(gatherK, dim3(NROWS / 4), dim3(256), 0, stream, Hb, targets, cidx,
                     Hc1, Hc2);
  // head: all rows x cols [0,4002) (padded to 4096)
  hipLaunchKernelGGL(gemm_lse, dim3(16, CT_HEAD), dim3(512), 0, stream, Hb, Wb, 0,
                     CL_HEAD, biasr, ph, counts, 2);
  // tail1: cluster-1 rows x cols [4002,20002)
  hipLaunchKernelGGL(gemm_lse, dim3(16, CT_T1), dim3(512), 0, stream, Hc1, Wb, CB_T1,
                     CL_T1, biasr, pt1, counts, 0);
  // tail2: cluster-2 rows x cols [20002,50002) (padded to 30080)
  hipLaunchKernelGGL(gemm_lse, dim3(16, CT_T2), dim3(512), 0, stream, Hc2, Wb, CB_T2,
                     CL_T2, biasr, pt2, counts, 1);
  hipLaunchKernelGGL(rowloss, dim3(NROWS / 4), dim3(256), 0, stream, ph, pt1, pt2, cidx,
                     hiddens, weight, bias, tails, tail_bias, targets, losses);
  hipLaunchKernelGGL(meanloss, dim3(1), dim3(256), 0, stream, losses, out);
}

// Round 5
// 393.696 us; speedup vs baseline: 1.4350x; 1.3738x over previous
//
#include <hip/hip_runtime.h>
#include <hip/hip_bf16.h>
#include <cstdint>
#include <cstddef>

#define VV 50000
#define HH 1024
#define NROWS 4096
#define VPAD 50176      // padded reordered-W rows
#define SP1 4000
#define SP2 20000
#define SP3 50000

#define BM 256
#define BN 128
#define BK 64
#define NKT (HH / BK)           // 16
#define A_SLOT_E (BM * BK)      // 16384 elems
#define B_SLOT_E (BN * BK)      // 8192 elems
#define SLOT_E (A_SLOT_E + B_SLOT_E)  // 24576 elems = 48 KiB

// reordered-W column map: [0..3999]=weight, [4000..4001]=tail_vectors,
// [4002..50001]=weight[4000..49999], rest zero-pad
#define CB_T1 4002
#define CB_T2 20002
#define CL_HEAD 4002
#define CL_T1 20002
#define CL_T2 50002
#define CT_HEAD 32
#define CT_T1 125
#define CT_T2 235
#define PH_STRIDE 64    // 2*CT_HEAD
#define PT1_STRIDE 250  // 2*CT_T1
#define PT2_STRIDE 470  // 2*CT_T2

typedef __attribute__((ext_vector_type(8))) short short8;
typedef __attribute__((ext_vector_type(4))) float f32x4;
typedef __attribute__((ext_vector_type(4))) unsigned short us4;

typedef __attribute__((address_space(1))) unsigned int uint_g;
typedef __attribute__((address_space(3))) unsigned int uint_l;

__device__ __forceinline__ void gload16(const void* g, void* l) {
  __builtin_amdgcn_global_load_lds((const uint_g*)g, (uint_l*)l, 16, 0, 0);
}

__device__ __forceinline__ unsigned short f2bf(float f) {
  __hip_bfloat16 h = __float2bfloat16(f);
  return *reinterpret_cast<unsigned short*>(&h);
}

// ---- convert weight + tail_vectors -> bf16, reordered, padded to VPAD rows ----
__global__ void convW(const float* __restrict__ w, const float* __restrict__ tails,
                      unsigned short* __restrict__ Wb) {
  const size_t nq = (size_t)VPAD * HH / 4;
  for (size_t q = (size_t)blockIdx.x * blockDim.x + threadIdx.x; q < nq;
       q += (size_t)gridDim.x * blockDim.x) {
    const size_t e = q * 4;
    const int row = (int)(e >> 10);
    us4 o;
    if (row < 4000) {
      float4 f = *(const float4*)(w + e);
      o = (us4){f2bf(f.x), f2bf(f.y), f2bf(f.z), f2bf(f.w)};
    } else if (row < 4002) {
      float4 f = *(const float4*)(tails + (e - (size_t)4000 * HH));
      o = (us4){f2bf(f.x), f2bf(f.y), f2bf(f.z), f2bf(f.w)};
    } else if (row < 50002) {
      float4 f = *(const float4*)(w + (e - 2048));
      o = (us4){f2bf(f.x), f2bf(f.y), f2bf(f.z), f2bf(f.w)};
    } else {
      o = (us4){0, 0, 0, 0};
    }
    *(us4*)(Wb + e) = o;
  }
}

// reordered bias (pads get -1e30 so exp() underflows to 0)
__global__ void biasK(const float* __restrict__ bias, const float* __restrict__ tb,
                      float* __restrict__ biasr) {
  const int r = blockIdx.x * 256 + threadIdx.x;
  if (r >= VPAD) return;
  float v;
  if (r < 4000) v = bias[r];
  else if (r == 4000) v = tb[0];
  else if (r == 4001) v = tb[1];
  else if (r < 50002) v = bias[r - 2];
  else v = -1e30f;
  biasr[r] = v;
}

__global__ void convH(const float* __restrict__ h, unsigned short* __restrict__ Hb) {
  const size_t nq = (size_t)NROWS * HH / 4;
  for (size_t q = (size_t)blockIdx.x * blockDim.x + threadIdx.x; q < nq;
       q += (size_t)gridDim.x * blockDim.x) {
    const size_t e = q * 4;
    float4 f = *(const float4*)(h + e);
    us4 o = (us4){f2bf(f.x), f2bf(f.y), f2bf(f.z), f2bf(f.w)};
    *(us4*)(Hb + e) = o;
  }
}

// ---- deterministic cluster scan: compact index per row, counts ----
__global__ __launch_bounds__(1024) void scanK(const int* __restrict__ targets,
                                              int* __restrict__ cidx,
                                              int* __restrict__ counts) {
  __shared__ int s1[1024], s2[1024];
  const int tid = threadIdx.x;
  int c[4];
  int n1 = 0, n2 = 0;
#pragma unroll
  for (int j = 0; j < 4; j++) {
    const int t = targets[tid * 4 + j];
    c[j] = (t >= SP1) + (t >= SP2);
    n1 += (c[j] == 1);
    n2 += (c[j] == 2);
  }
  s1[tid] = n1;
  s2[tid] = n2;
  __syncthreads();
  for (int off = 1; off < 1024; off <<= 1) {
    const int a1 = (tid >= off) ? s1[tid - off] : 0;
    const int a2 = (tid >= off) ? s2[tid - off] : 0;
    __syncthreads();
    s1[tid] += a1;
    s2[tid] += a2;
    __syncthreads();
  }
  int e1 = s1[tid] - n1, e2 = s2[tid] - n2;
#pragma unroll
  for (int j = 0; j < 4; j++) {
    if (c[j] == 1) cidx[tid * 4 + j] = e1++;
    else if (c[j] == 2) cidx[tid * 4 + j] = e2++;
    else cidx[tid * 4 + j] = 0;
  }
  if (tid == 1023) {
    counts[0] = s1[1023];
    counts[1] = s2[1023];
    counts[2] = NROWS;
  }
}

// zero both compact-H buffers (contiguous)
__global__ void zeroHc(unsigned short* __restrict__ Hc) {
  const size_t n8 = (size_t)2 * NROWS * HH / 8;
  const short8 z = (short8){0, 0, 0, 0, 0, 0, 0, 0};
  for (size_t i = (size_t)blockIdx.x * blockDim.x + threadIdx.x; i < n8;
       i += (size_t)gridDim.x * blockDim.x)
    *((short8*)Hc + i) = z;
}

// gather bf16 H rows into per-cluster compact matrices (1 wave per row)
__global__ __launch_bounds__(256) void gatherK(const unsigned short* __restrict__ Hb,
                                               const int* __restrict__ targets,
                                               const int* __restrict__ cidx,
                                               unsigned short* __restrict__ Hc1,
                                               unsigned short* __restrict__ Hc2) {
  const int row = blockIdx.x * 4 + (threadIdx.x >> 6);
  const int lane = threadIdx.x & 63;
  const int t = targets[row];
  const int cl = (t >= SP1) + (t >= SP2);
  if (cl == 0) return;
  unsigned short* dst = (cl == 1 ? Hc1 : Hc2) + (size_t)cidx[row] * HH;
  const unsigned short* src = Hb + (size_t)row * HH;
#pragma unroll
  for (int j = 0; j < 2; j++) {
    const int i = j * 512 + lane * 8;
    *(short8*)(dst + i) = *(const short8*)(src + i);
  }
}

// ---- GEMM + single-segment sum-exp epilogue ----
// 1-D grid = 16*CT blocks, colTile FASTEST (bid = rowTile*CT + colTile) so
// early-exit rowTiles are a trailing contiguous range -> even XCD balance.
// 512 threads (8 waves = 4M x 2N, wave 64x64); 3-slot LDS ring, distance-2
// prefetch, counted vmcnt(6), XOR-swizzle (0 bank conflicts).
__global__ __launch_bounds__(512) void gemm_lse(
    const unsigned short* __restrict__ Ab, const unsigned short* __restrict__ Wb,
    int CT, int colbase, int col_limit, const float* __restrict__ biasr,
    float* __restrict__ partials, const int* __restrict__ Mptr, int mslot) {
  const int Mc = Mptr[mslot];
  const int bid = blockIdx.x;
  const int rowTile = bid / CT;
  const int colTile = bid - rowTile * CT;
  if (rowTile * BM >= Mc) return;

  __shared__ __align__(16) unsigned short lds[3 * SLOT_E];  // 147456 B

  const int tid = threadIdx.x;
  const int w = tid >> 6, lane = tid & 63;
  const int wr = w >> 1, wc = w & 1;
  const int fr = lane & 15, fq = lane >> 4;
  const unsigned short* Ag = Ab + (size_t)rowTile * BM * HH;
  const unsigned short* Bg = Wb + (size_t)(colbase + colTile * BN) * HH;

  // staging offsets: linear LDS dest, inverse-swizzled global source
  int srcA[4], srcB[2];
  const int dcb = (tid & 7) << 4;  // dest byte-col within 128B row
#pragma unroll
  for (int i = 0; i < 4; i++) {
    const int R = (i * 512 + tid) >> 3;
    srcA[i] = R * HH + ((dcb ^ ((R & 7) << 4)) >> 1);
  }
#pragma unroll
  for (int i = 0; i < 2; i++) {
    const int R = (i * 512 + tid) >> 3;
    srcB[i] = R * HH + ((dcb ^ ((R & 7) << 4)) >> 1);
  }

  // fragment read offsets (swizzled), elements within slot
  int offA[4][2], offB[4][2];
#pragma unroll
  for (int mi = 0; mi < 4; mi++) {
    const int R = wr * 64 + mi * 16 + fr;
#pragma unroll
    for (int kk = 0; kk < 2; kk++) {
      const int cb = kk * 64 + fq * 16;
      offA[mi][kk] = R * 64 + ((cb ^ ((R & 7) << 4)) >> 1);
    }
  }
#pragma unroll
  for (int ni = 0; ni < 4; ni++) {
    const int R = wc * 64 + ni * 16 + fr;
#pragma unroll
    for (int kk = 0; kk < 2; kk++) {
      const int cb = kk * 64 + fq * 16;
      offB[ni][kk] = R * 64 + ((cb ^ ((R & 7) << 4)) >> 1);
    }
  }

  f32x4 acc[4][4];
#pragma unroll
  for (int i = 0; i < 4; i++)
#pragma unroll
    for (int j = 0; j < 4; j++) acc[i][j] = (f32x4){0.f, 0.f, 0.f, 0.f};

  auto STAGE = [&](int t) {
    const int slot = t % 3;
    unsigned short* Asl = (unsigned short*)lds + slot * SLOT_E;
    unsigned short* Bsl = Asl + A_SLOT_E;
    const int k0 = t * BK;
#pragma unroll
    for (int i = 0; i < 4; i++)
      gload16(Ag + (size_t)srcA[i] + k0, Asl + (i * 512 + tid) * 8);
#pragma unroll
    for (int i = 0; i < 2; i++)
      gload16(Bg + (size_t)srcB[i] + k0, Bsl + (i * 512 + tid) * 8);
  };

  STAGE(0);
  STAGE(1);

  for (int t = 0; t < NKT; ++t) {
    if (t < NKT - 1)
      asm volatile("s_waitcnt vmcnt(6)" ::: "memory");
    else
      asm volatile("s_waitcnt vmcnt(0)" ::: "memory");
    __builtin_amdgcn_s_barrier();
    if (t + 2 < NKT) STAGE(t + 2);

    const unsigned short* Asl = (const unsigned short*)lds + (t % 3) * SLOT_E;
    const unsigned short* Bsl = Asl + A_SLOT_E;
#pragma unroll
    for (int kk = 0; kk < 2; kk++) {
      short8 a[4], b[4];
#pragma unroll
      for (int mi = 0; mi < 4; mi++) a[mi] = *(const short8*)&Asl[offA[mi][kk]];
#pragma unroll
      for (int ni = 0; ni < 4; ni++) b[ni] = *(const short8*)&Bsl[offB[ni][kk]];
      __builtin_amdgcn_s_setprio(1);
#pragma unroll
      for (int mi = 0; mi < 4; mi++)
#pragma unroll
        for (int ni = 0; ni < 4; ni++)
          acc[mi][ni] =
              __builtin_amdgcn_mfma_f32_16x16x32_bf16(a[mi], b[ni], acc[mi][ni], 0, 0, 0);
      __builtin_amdgcn_s_setprio(0);
    }
    __builtin_amdgcn_s_barrier();
  }

  // ---- epilogue: per-(row, 64-col chunk) sum of exp(logit + bias) ----
  const int colw = colTile * BN + wc * 64;
  float biasv[4];
#pragma unroll
  for (int ni = 0; ni < 4; ni++) {
    const int gcol = colbase + colw + ni * 16 + fr;
    biasv[ni] = (gcol < col_limit) ? biasr[gcol] : -1e30f;
  }
  const int chunk = colTile * 2 + wc;
  const int pstride = CT * 2;

#pragma unroll
  for (int mi = 0; mi < 4; mi++) {
    const int rowg = rowTile * BM + wr * 64 + mi * 16 + fq * 4;
#pragma unroll
    for (int r = 0; r < 4; r++) {
      float p = 0.f;
#pragma unroll
      for (int ni = 0; ni < 4; ni++) p += __expf(acc[mi][ni][r] + biasv[ni]);
#pragma unroll
      for (int m = 1; m < 16; m <<= 1) p += __shfl_xor(p, m);
      if (fr == 0) partials[(size_t)(rowg + r) * pstride + chunk] = p;
    }
  }
}

// ---- per-row: combine chunk partials, selected logits in fp32, loss ----
__global__ __launch_bounds__(256) void rowloss(
    const float* __restrict__ ph, const float* __restrict__ pt1,
    const float* __restrict__ pt2, const int* __restrict__ cidx,
    const float* __restrict__ hiddens, const float* __restrict__ weight,
    const float* __restrict__ bias, const float* __restrict__ tails,
    const float* __restrict__ tail_bias, const int* __restrict__ targets,
    float* __restrict__ losses) {
  const int row = blockIdx.x * 4 + (threadIdx.x >> 6);
  const int lane = threadIdx.x & 63;
  const int t = targets[row];
  const int cl = (t >= SP1) + (t >= SP2);

  float s0 = ph[(size_t)row * PH_STRIDE + lane];  // exactly 64 chunks
  float st = 0.f;
  if (cl == 1) {
    const float* P = pt1 + (size_t)cidx[row] * PT1_STRIDE;
    for (int c = lane; c < PT1_STRIDE; c += 64) st += P[c];
  } else if (cl == 2) {
    const float* P = pt2 + (size_t)cidx[row] * PT2_STRIDE;
    for (int c = lane; c < PT2_STRIDE; c += 64) st += P[c];
  }
#pragma unroll
  for (int m = 1; m < 64; m <<= 1) {
    s0 += __shfl_xor(s0, m);
    st += __shfl_xor(st, m);
  }

  const float* hv = hiddens + (size_t)row * HH;
  const float* w1;
  float b1;
  if (cl == 0) {
    w1 = weight + (size_t)t * HH;
    b1 = bias[t];
  } else if (cl == 1) {
    w1 = tails + HH;  // head col 4001 <-> tail_vectors[1]
    b1 = tail_bias[1];
  } else {
    w1 = tails;       // head col 4000 <-> tail_vectors[0]
    b1 = tail_bias[0];
  }
  float d1 = 0.f, d2 = 0.f;
  for (int i = lane; i < HH; i += 64) d1 += hv[i] * w1[i];
  if (cl > 0) {
    const float* w2 = weight + (size_t)t * HH;
    for (int i = lane; i < HH; i += 64) d2 += hv[i] * w2[i];
  }
#pragma unroll
  for (int m = 1; m < 64; m <<= 1) {
    d1 += __shfl_xor(d1, m);
    d2 += __shfl_xor(d2, m);
  }
  if (lane == 0) {
    float loss = logf(s0) - (d1 + b1);
    if (cl > 0) loss += logf(st) - (d2 + bias[t]);
    losses[row] = loss;
  }
}

__global__ void meanloss(const float* __restrict__ losses, float* __restrict__ out) {
  __shared__ float red[256];
  float s = 0.f;
  for (int i = threadIdx.x; i < NROWS; i += 256) s += losses[i];
  red[threadIdx.x] = s;
  __syncthreads();
  for (int st = 128; st > 0; st >>= 1) {
    if ((int)threadIdx.x < st) red[threadIdx.x] += red[threadIdx.x + st];
    __syncthreads();
  }
  if (threadIdx.x == 0) out[0] = red[0] / (float)NROWS;
}

extern "C" void kernel_launch(void* const* d_in, const int* in_sizes, int n_in,
                              void* d_out, int out_size, void* d_ws, size_t ws_size,
                              hipStream_t stream) {
  const float* weight = (const float*)d_in[0];
  const float* bias = (const float*)d_in[1];
  const float* hiddens = (const float*)d_in[2];
  const float* tails = (const float*)d_in[3];
  const float* tail_bias = (const float*)d_in[4];
  const int* targets = (const int*)d_in[5];
  float* out = (float*)d_out;

  char* ws = (char*)d_ws;
  unsigned short* Wb = (unsigned short*)ws;                     // 50176*1024*2 = 102,760,448
  unsigned short* Hb = (unsigned short*)(ws + 102760448);       //  8,388,608
  unsigned short* Hc1 = (unsigned short*)(ws + 111149056);      //  8,388,608
  unsigned short* Hc2 = (unsigned short*)(ws + 119537664);      //  8,388,608 (contig w/ Hc1)
  float* ph = (float*)(ws + 127926272);                         //  4096*64*4  = 1,048,576
  float* pt1 = (float*)(ws + 128974848);                        //  4096*250*4 = 4,096,000
  float* pt2 = (float*)(ws + 133070848);                        //  4096*470*4 = 7,700,480
  float* biasr = (float*)(ws + 140771328);                      //  50176*4    = 200,704
  int* cidx = (int*)(ws + 140972032);                           //  16,384
  int* counts = (int*)(ws + 140988416);                         //  64
  float* losses = (float*)(ws + 140988480);                     //  16,384

  hipLaunchKernelGGL(convW, dim3(2048), dim3(256), 0, stream, weight, tails, Wb);
  hipLaunchKernelGGL(biasK, dim3((VPAD + 255) / 256), dim3(256), 0, stream, bias,
                     tail_bias, biasr);
  hipLaunchKernelGGL(convH, dim3(512), dim3(256), 0, stream, hiddens, Hb);
  hipLaunchKernelGGL(scanK, dim3(1), dim3(1024), 0, stream, targets, cidx, counts);
  hipLaunchKernelGGL(zeroHc, dim3(1024), dim3(256), 0, stream, Hc1);
  hipLaunchKernelGGL(gatherK, dim3(NROWS / 4), dim3(256), 0, stream, Hb, targets, cidx,
                     Hc1, Hc2);
  // head: all rows x cols [0,4002) (padded to 4096)
  hipLaunchKernelGGL(gemm_lse, dim3(16 * CT_HEAD), dim3(512), 0, stream, Hb, Wb,
                     CT_HEAD, 0, CL_HEAD, biasr, ph, counts, 2);
  // tail1: cluster-1 rows x cols [4002,20002)
  hipLaunchKernelGGL(gemm_lse, dim3(16 * CT_T1), dim3(512), 0, stream, Hc1, Wb, CT_T1,
                     CB_T1, CL_T1, biasr, pt1, counts, 0);
  // tail2: cluster-2 rows x cols [20002,50002) (padded to 30080)
  hipLaunchKernelGGL(gemm_lse, dim3(16 * CT_T2), dim3(512), 0, stream, Hc2, Wb, CT_T2,
                     CB_T2, CL_T2, biasr, pt2, counts, 1);
  hipLaunchKernelGGL(rowloss, dim3(NROWS / 4), dim3(256), 0, stream, ph, pt1, pt2, cidx,
                     hiddens, weight, bias, tails, tail_bias, targets, losses);
  hipLaunchKernelGGL(meanloss, dim3(1), dim3(256), 0, stream, losses, out);
}

// Round 6
// 312.153 us; speedup vs baseline: 1.8099x; 1.2612x over previous
//
#include <hip/hip_runtime.h>
#include <hip/hip_bf16.h>
#include <cstdint>
#include <cstddef>

#define VV 50000
#define HH 1024
#define NROWS 4096
#define VPAD 50176      // padded reordered-W rows
#define SP1 4000
#define SP2 20000
#define SP3 50000

#define BM 256
#define BN 128
#define BK 64
#define NKT (HH / BK)           // 16
#define A_SLOT_B (BM * BK)      // 16384 bytes (fp8)
#define B_SLOT_B (BN * BK)      // 8192 bytes
#define SLOT_B (A_SLOT_B + B_SLOT_B)  // 24576 B/slot, 3 slots = 72 KiB

// reordered-W column map: [0..3999]=weight, [4000..4001]=tail_vectors,
// [4002..50001]=weight[4000..49999], rest zero-pad
#define CB_T1 4002
#define CB_T2 20002
#define CL_HEAD 4002
#define CL_T1 20002
#define CL_T2 50002
#define CT_HEAD 32
#define CT_T1 125
#define CT_T2 235
#define PH_STRIDE 64    // 2*CT_HEAD
#define PT1_STRIDE 250  // 2*CT_T1
#define PT2_STRIDE 470  // 2*CT_T2

#define WSCALE 256.0f
#define HSCALE 16.0f
#define INVSCALE (1.0f / 4096.0f)

typedef __attribute__((ext_vector_type(2))) long long2v;
typedef __attribute__((ext_vector_type(4))) float f32x4;

typedef __attribute__((address_space(1))) unsigned int uint_g;
typedef __attribute__((address_space(3))) unsigned int uint_l;

__device__ __forceinline__ void gload16(const void* g, void* l) {
  __builtin_amdgcn_global_load_lds((const uint_g*)g, (uint_l*)l, 16, 0, 0);
}

// K-permutation within a 64-col tile: orig k -> stored byte p, so that one
// 16-B LDS read at p=fq*16 yields both K=32-block fragments for lane group fq.
__device__ __forceinline__ int kperm(int o6) {
  return (((o6 >> 3) & 3) << 4) | ((o6 >> 5) << 3) | (o6 & 7);
}

// pack 4 floats -> 4 fp8 e4m3 bytes
__device__ __forceinline__ unsigned int pk4(float a, float b, float c, float d) {
  int p = __builtin_amdgcn_cvt_pk_fp8_f32(a, b, 0, 0);
  p = __builtin_amdgcn_cvt_pk_fp8_f32(c, d, p, 1);
  return (unsigned int)p;
}

// ---- convert weight + tail_vectors -> fp8 (x256), reordered rows, K-permuted ----
__global__ void convW(const float* __restrict__ w, const float* __restrict__ tails,
                      unsigned char* __restrict__ Wf) {
  const size_t nq = (size_t)VPAD * HH / 4;
  for (size_t q = (size_t)blockIdx.x * blockDim.x + threadIdx.x; q < nq;
       q += (size_t)gridDim.x * blockDim.x) {
    const size_t e = q * 4;
    const int row = (int)(e >> 10);
    const int off = (int)(e & 1023);
    unsigned int o;
    if (row < 4000) {
      float4 f = *(const float4*)(w + e);
      o = pk4(f.x * WSCALE, f.y * WSCALE, f.z * WSCALE, f.w * WSCALE);
    } else if (row < 4002) {
      float4 f = *(const float4*)(tails + (e - (size_t)4000 * HH));
      o = pk4(f.x * WSCALE, f.y * WSCALE, f.z * WSCALE, f.w * WSCALE);
    } else if (row < 50002) {
      float4 f = *(const float4*)(w + (e - 2048));
      o = pk4(f.x * WSCALE, f.y * WSCALE, f.z * WSCALE, f.w * WSCALE);
    } else {
      o = 0u;
    }
    const int p = (off & ~63) | kperm(off & 63);
    *(unsigned int*)(Wf + (size_t)row * HH + p) = o;
  }
}

// reordered bias (pads get -1e30 so exp() underflows to 0)
__global__ void biasK(const float* __restrict__ bias, const float* __restrict__ tb,
                      float* __restrict__ biasr) {
  const int r = blockIdx.x * 256 + threadIdx.x;
  if (r >= VPAD) return;
  float v;
  if (r < 4000) v = bias[r];
  else if (r == 4000) v = tb[0];
  else if (r == 4001) v = tb[1];
  else if (r < 50002) v = bias[r - 2];
  else v = -1e30f;
  biasr[r] = v;
}

__global__ void convH(const float* __restrict__ h, unsigned char* __restrict__ Hf) {
  const size_t nq = (size_t)NROWS * HH / 4;
  for (size_t q = (size_t)blockIdx.x * blockDim.x + threadIdx.x; q < nq;
       q += (size_t)gridDim.x * blockDim.x) {
    const size_t e = q * 4;
    const int row = (int)(e >> 10);
    const int off = (int)(e & 1023);
    float4 f = *(const float4*)(h + e);
    unsigned int o = pk4(f.x * HSCALE, f.y * HSCALE, f.z * HSCALE, f.w * HSCALE);
    const int p = (off & ~63) | kperm(off & 63);
    *(unsigned int*)(Hf + (size_t)row * HH + p) = o;
  }
}

// ---- deterministic cluster scan: compact index per row, counts ----
__global__ __launch_bounds__(1024) void scanK(const int* __restrict__ targets,
                                              int* __restrict__ cidx,
                                              int* __restrict__ counts) {
  __shared__ int s1[1024], s2[1024];
  const int tid = threadIdx.x;
  int c[4];
  int n1 = 0, n2 = 0;
#pragma unroll
  for (int j = 0; j < 4; j++) {
    const int t = targets[tid * 4 + j];
    c[j] = (t >= SP1) + (t >= SP2);
    n1 += (c[j] == 1);
    n2 += (c[j] == 2);
  }
  s1[tid] = n1;
  s2[tid] = n2;
  __syncthreads();
  for (int off = 1; off < 1024; off <<= 1) {
    const int a1 = (tid >= off) ? s1[tid - off] : 0;
    const int a2 = (tid >= off) ? s2[tid - off] : 0;
    __syncthreads();
    s1[tid] += a1;
    s2[tid] += a2;
    __syncthreads();
  }
  int e1 = s1[tid] - n1, e2 = s2[tid] - n2;
#pragma unroll
  for (int j = 0; j < 4; j++) {
    if (c[j] == 1) cidx[tid * 4 + j] = e1++;
    else if (c[j] == 2) cidx[tid * 4 + j] = e2++;
    else cidx[tid * 4 + j] = 0;
  }
  if (tid == 1023) {
    counts[0] = s1[1023];
    counts[1] = s2[1023];
    counts[2] = NROWS;
  }
}

// zero both compact-H fp8 buffers (contiguous)
__global__ void zeroHc(uint4* __restrict__ Hc) {
  const size_t n16 = (size_t)2 * NROWS * HH / 16;
  const uint4 z = {0u, 0u, 0u, 0u};
  for (size_t i = (size_t)blockIdx.x * blockDim.x + threadIdx.x; i < n16;
       i += (size_t)gridDim.x * blockDim.x)
    Hc[i] = z;
}

// gather fp8 H rows into per-cluster compact matrices (1 wave per row)
__global__ __launch_bounds__(256) void gatherK(const unsigned char* __restrict__ Hf,
                                               const int* __restrict__ targets,
                                               const int* __restrict__ cidx,
                                               unsigned char* __restrict__ Hc1,
                                               unsigned char* __restrict__ Hc2) {
  const int row = blockIdx.x * 4 + (threadIdx.x >> 6);
  const int lane = threadIdx.x & 63;
  const int t = targets[row];
  const int cl = (t >= SP1) + (t >= SP2);
  if (cl == 0) return;
  unsigned char* dst = (cl == 1 ? Hc1 : Hc2) + (size_t)cidx[row] * HH;
  const unsigned char* src = Hf + (size_t)row * HH;
  *(uint4*)(dst + lane * 16) = *(const uint4*)(src + lane * 16);
}

// ---- fp8 GEMM + single-segment sum-exp epilogue ----
// 1-D grid, colTile fastest (bid = rowTile*CT + colTile), trailing early-exit.
// 512 threads (8 waves = 4M x 2N, wave 64x64); 3-slot LDS ring (72 KiB ->
// 2 blocks/CU), distance-2 prefetch, counted vmcnt(3).
// LDS layout per tile row R, permuted byte p (K-perm done at conversion):
//   off(R,p) = (R>>1)*128 + (R&1)*64 + (p ^ (((R>>1)&3)<<4))
// -> fragment ds_read_b128 at p=fq*16 spreads 16 lanes over 8 16-B slots
//    (2-way = free); one read yields both K=32-block fragments (long2).
__global__ __launch_bounds__(512) void gemm_lse(
    const unsigned char* __restrict__ Ab, const unsigned char* __restrict__ Wf,
    int CT, int colbase, int col_limit, const float* __restrict__ biasr,
    float* __restrict__ partials, const int* __restrict__ Mptr, int mslot) {
  const int Mc = Mptr[mslot];
  const int bid = blockIdx.x;
  const int rowTile = bid / CT;
  const int colTile = bid - rowTile * CT;
  if (rowTile * BM >= Mc) return;

  __shared__ __align__(16) unsigned char lds[3 * SLOT_B];  // 73728 B

  const int tid = threadIdx.x;
  const int w = tid >> 6, lane = tid & 63;
  const int wr = w >> 1, wc = w & 1;
  const int fr = lane & 15, fq = lane >> 4;
  const unsigned char* Ag = Ab + (size_t)rowTile * BM * HH;
  const unsigned char* Bg = Wf + (size_t)(colbase + colTile * BN) * HH;

  // staging source offsets (bytes): invert LDS layout for linear 16-B chunks
  int srcA[2], srcB;
  {
#pragma unroll
    for (int i = 0; i < 2; i++) {
      const int c8 = i * 512 + tid;
      const int rp = c8 >> 3;
      const int R = 2 * rp + ((c8 >> 2) & 1);
      const int p = ((c8 & 3) ^ (rp & 3)) * 16;
      srcA[i] = R * HH + p;
    }
    const int c8 = tid;
    const int rp = c8 >> 3;
    const int R = 2 * rp + ((c8 >> 2) & 1);
    const int p = ((c8 & 3) ^ (rp & 3)) * 16;
    srcB = R * HH + p;
  }

  // fragment read offsets (bytes within slot)
  int offA[4], offB[4];
#pragma unroll
  for (int mi = 0; mi < 4; mi++) {
    const int R = wr * 64 + mi * 16 + fr;
    offA[mi] = (R >> 1) * 128 + (R & 1) * 64 + ((fq ^ ((R >> 1) & 3)) << 4);
  }
#pragma unroll
  for (int ni = 0; ni < 4; ni++) {
    const int R = wc * 64 + ni * 16 + fr;
    offB[ni] = (R >> 1) * 128 + (R & 1) * 64 + ((fq ^ ((R >> 1) & 3)) << 4);
  }

  f32x4 acc[4][4];
#pragma unroll
  for (int i = 0; i < 4; i++)
#pragma unroll
    for (int j = 0; j < 4; j++) acc[i][j] = (f32x4){0.f, 0.f, 0.f, 0.f};

  auto STAGE = [&](int t) {
    const int slot = t % 3;
    unsigned char* Asl = lds + slot * SLOT_B;
    unsigned char* Bsl = Asl + A_SLOT_B;
    const int k0 = t * BK;  // byte offset (1 B/elem)
#pragma unroll
    for (int i = 0; i < 2; i++)
      gload16(Ag + (size_t)srcA[i] + k0, Asl + (i * 512 + tid) * 16);
    gload16(Bg + (size_t)srcB + k0, Bsl + tid * 16);
  };

  STAGE(0);
  STAGE(1);

  for (int t = 0; t < NKT; ++t) {
    if (t < NKT - 1)
      asm volatile("s_waitcnt vmcnt(3)" ::: "memory");
    else
      asm volatile("s_waitcnt vmcnt(0)" ::: "memory");
    __builtin_amdgcn_s_barrier();
    if (t + 2 < NKT) STAGE(t + 2);

    const unsigned char* Asl = lds + (t % 3) * SLOT_B;
    const unsigned char* Bsl = Asl + A_SLOT_B;
    long2v a2[4], b2[4];
#pragma unroll
    for (int mi = 0; mi < 4; mi++) a2[mi] = *(const long2v*)(Asl + offA[mi]);
#pragma unroll
    for (int ni = 0; ni < 4; ni++) b2[ni] = *(const long2v*)(Bsl + offB[ni]);
    __builtin_amdgcn_s_setprio(1);
#pragma unroll
    for (int mi = 0; mi < 4; mi++)
#pragma unroll
      for (int ni = 0; ni < 4; ni++)
        acc[mi][ni] = __builtin_amdgcn_mfma_f32_16x16x32_fp8_fp8(
            a2[mi].x, b2[ni].x, acc[mi][ni], 0, 0, 0);
#pragma unroll
    for (int mi = 0; mi < 4; mi++)
#pragma unroll
      for (int ni = 0; ni < 4; ni++)
        acc[mi][ni] = __builtin_amdgcn_mfma_f32_16x16x32_fp8_fp8(
            a2[mi].y, b2[ni].y, acc[mi][ni], 0, 0, 0);
    __builtin_amdgcn_s_setprio(0);
    __builtin_amdgcn_s_barrier();
  }

  // ---- epilogue: per-(row, 64-col chunk) sum of exp(logit/4096 + bias) ----
  const int colw = colTile * BN + wc * 64;
  float biasv[4];
#pragma unroll
  for (int ni = 0; ni < 4; ni++) {
    const int gcol = colbase + colw + ni * 16 + fr;
    biasv[ni] = (gcol < col_limit) ? biasr[gcol] : -1e30f;
  }
  const int chunk = colTile * 2 + wc;
  const int pstride = CT * 2;

#pragma unroll
  for (int mi = 0; mi < 4; mi++) {
    const int rowg = rowTile * BM + wr * 64 + mi * 16 + fq * 4;
#pragma unroll
    for (int r = 0; r < 4; r++) {
      float p = 0.f;
#pragma unroll
      for (int ni = 0; ni < 4; ni++)
        p += __expf(acc[mi][ni][r] * INVSCALE + biasv[ni]);
#pragma unroll
      for (int m = 1; m < 16; m <<= 1) p += __shfl_xor(p, m);
      if (fr == 0) partials[(size_t)(rowg + r) * pstride + chunk] = p;
    }
  }
}

// ---- per-row: combine chunk partials, selected logits in fp32, loss ----
__global__ __launch_bounds__(256) void rowloss(
    const float* __restrict__ ph, const float* __restrict__ pt1,
    const float* __restrict__ pt2, const int* __restrict__ cidx,
    const float* __restrict__ hiddens, const float* __restrict__ weight,
    const float* __restrict__ bias, const float* __restrict__ tails,
    const float* __restrict__ tail_bias, const int* __restrict__ targets,
    float* __restrict__ losses) {
  const int row = blockIdx.x * 4 + (threadIdx.x >> 6);
  const int lane = threadIdx.x & 63;
  const int t = targets[row];
  const int cl = (t >= SP1) + (t >= SP2);

  float s0 = ph[(size_t)row * PH_STRIDE + lane];  // exactly 64 chunks
  float st = 0.f;
  if (cl == 1) {
    const float* P = pt1 + (size_t)cidx[row] * PT1_STRIDE;
    for (int c = lane; c < PT1_STRIDE; c += 64) st += P[c];
  } else if (cl == 2) {
    const float* P = pt2 + (size_t)cidx[row] * PT2_STRIDE;
    for (int c = lane; c < PT2_STRIDE; c += 64) st += P[c];
  }
#pragma unroll
  for (int m = 1; m < 64; m <<= 1) {
    s0 += __shfl_xor(s0, m);
    st += __shfl_xor(st, m);
  }

  const float* hv = hiddens + (size_t)row * HH;
  const float* w1;
  float b1;
  if (cl == 0) {
    w1 = weight + (size_t)t * HH;
    b1 = bias[t];
  } else if (cl == 1) {
    w1 = tails + HH;  // head col 4001 <-> tail_vectors[1]
    b1 = tail_bias[1];
  } else {
    w1 = tails;       // head col 4000 <-> tail_vectors[0]
    b1 = tail_bias[0];
  }
  float d1 = 0.f, d2 = 0.f;
  for (int i = lane; i < HH; i += 64) d1 += hv[i] * w1[i];
  if (cl > 0) {
    const float* w2 = weight + (size_t)t * HH;
    for (int i = lane; i < HH; i += 64) d2 += hv[i] * w2[i];
  }
#pragma unroll
  for (int m = 1; m < 64; m <<= 1) {
    d1 += __shfl_xor(d1, m);
    d2 += __shfl_xor(d2, m);
  }
  if (lane == 0) {
    float loss = logf(s0) - (d1 + b1);
    if (cl > 0) loss += logf(st) - (d2 + bias[t]);
    losses[row] = loss;
  }
}

__global__ void meanloss(const float* __restrict__ losses, float* __restrict__ out) {
  __shared__ float red[256];
  float s = 0.f;
  for (int i = threadIdx.x; i < NROWS; i += 256) s += losses[i];
  red[threadIdx.x] = s;
  __syncthreads();
  for (int st = 128; st > 0; st >>= 1) {
    if ((int)threadIdx.x < st) red[threadIdx.x] += red[threadIdx.x + st];
    __syncthreads();
  }
  if (threadIdx.x == 0) out[0] = red[0] / (float)NROWS;
}

extern "C" void kernel_launch(void* const* d_in, const int* in_sizes, int n_in,
                              void* d_out, int out_size, void* d_ws, size_t ws_size,
                              hipStream_t stream) {
  const float* weight = (const float*)d_in[0];
  const float* bias = (const float*)d_in[1];
  const float* hiddens = (const float*)d_in[2];
  const float* tails = (const float*)d_in[3];
  const float* tail_bias = (const float*)d_in[4];
  const int* targets = (const int*)d_in[5];
  float* out = (float*)d_out;

  char* ws = (char*)d_ws;
  unsigned char* Wf = (unsigned char*)ws;                      // 50176*1024 = 51,380,224
  unsigned char* Hf = (unsigned char*)(ws + 51380224);         //  4,194,304
  unsigned char* Hc1 = (unsigned char*)(ws + 55574528);        //  4,194,304
  unsigned char* Hc2 = (unsigned char*)(ws + 59768832);        //  4,194,304 (contig w/ Hc1)
  float* ph = (float*)(ws + 63963136);                         //  4096*64*4  = 1,048,576
  float* pt1 = (float*)(ws + 65011712);                        //  4096*250*4 = 4,096,000
  float* pt2 = (float*)(ws + 69107712);                        //  4096*470*4 = 7,700,480
  float* biasr = (float*)(ws + 76808192);                      //  50176*4    = 200,704
  int* cidx = (int*)(ws + 77008896);                           //  16,384
  int* counts = (int*)(ws + 77025280);                         //  64
  float* losses = (float*)(ws + 77025344);                     //  16,384

  hipLaunchKernelGGL(convW, dim3(2048), dim3(256), 0, stream, weight, tails, Wf);
  hipLaunchKernelGGL(biasK, dim3((VPAD + 255) / 256), dim3(256), 0, stream, bias,
                     tail_bias, biasr);
  hipLaunchKernelGGL(convH, dim3(512), dim3(256), 0, stream, hiddens, Hf);
  hipLaunchKernelGGL(scanK, dim3(1), dim3(1024), 0, stream, targets, cidx, counts);
  hipLaunchKernelGGL(zeroHc, dim3(1024), dim3(256), 0, stream, (uint4*)Hc1);
  hipLaunchKernelGGL(gatherK, dim3(NROWS / 4), dim3(256), 0, stream, Hf, targets, cidx,
                     Hc1, Hc2);
  // head: all rows x cols [0,4002) (padded to 4096)
  hipLaunchKernelGGL(gemm_lse, dim3(16 * CT_HEAD), dim3(512), 0, stream, Hf, Wf,
                     CT_HEAD, 0, CL_HEAD, biasr, ph, counts, 2);
  // tail1: cluster-1 rows x cols [4002,20002)
  hipLaunchKernelGGL(gemm_lse, dim3(16 * CT_T1), dim3(512), 0, stream, Hc1, Wf, CT_T1,
                     CB_T1, CL_T1, biasr, pt1, counts, 0);
  // tail2: cluster-2 rows x cols [20002,50002) (padded to 30080)
  hipLaunchKernelGGL(gemm_lse, dim3(16 * CT_T2), dim3(512), 0, stream, Hc2, Wf, CT_T2,
                     CB_T2, CL_T2, biasr, pt2, counts, 1);
  hipLaunchKernelGGL(rowloss, dim3(NROWS / 4), dim3(256), 0, stream, ph, pt1, pt2, cidx,
                     hiddens, weight, bias, tails, tail_bias, targets, losses);
  hipLaunchKernelGGL(meanloss, dim3(1), dim3(256), 0, stream, losses, out);
}